// Round 4
// baseline (609.478 us; speedup 1.0000x reference)
//
#include <hip/hip_runtime.h>
#include <hip/hip_bf16.h>

#define N_NODES 100000
#define N_EDGES 1600000
#define OUTF 128
#define INF 256
#define SCAN_CHUNK 1024
#define SCAN_BLOCKS 98   // 98*1024 = 100352 >= 100000
#define M_TILES 6250     // 100000 / 16  (exact)
#define E_BLOCKS 6250    // 1600000 / 256 (exact)

typedef _Float16 f16;
typedef _Float16 half8 __attribute__((ext_vector_type(8)));
typedef _Float16 half4 __attribute__((ext_vector_type(4)));
typedef _Float16 half2v __attribute__((ext_vector_type(2)));
typedef float floatx4 __attribute__((ext_vector_type(4)));

// ---------------- scan step 1: per-chunk sums ----------------
__global__ __launch_bounds__(256) void scan_partial_kernel(const int* __restrict__ deg, int n,
                                                           int* __restrict__ partial) {
    __shared__ int red[256];
    int b = blockIdx.x, t = threadIdx.x;
    int base = b * SCAN_CHUNK;
    int s = 0;
    for (int i = t; i < SCAN_CHUNK; i += 256) {
        int idx = base + i;
        if (idx < n) s += deg[idx];
    }
    red[t] = s;
    __syncthreads();
    for (int off = 128; off > 0; off >>= 1) {
        if (t < off) red[t] += red[t + off];
        __syncthreads();
    }
    if (t == 0) partial[b] = red[0];
}

// ---------------- scan step 2: exclusive scan of partials (nb <= 128) ----------------
__global__ __launch_bounds__(128) void scan_top_kernel(int* __restrict__ partial, int nb,
                                                       int* __restrict__ row_start, int n) {
    __shared__ int sc[128];
    int t = threadIdx.x;
    int v = (t < nb) ? partial[t] : 0;
    sc[t] = v;
    __syncthreads();
    for (int off = 1; off < 128; off <<= 1) {
        int val = sc[t];
        int add = (t >= off) ? sc[t - off] : 0;
        __syncthreads();
        sc[t] = val + add;
        __syncthreads();
    }
    if (t < nb) partial[t] = sc[t] - v;   // exclusive
    if (t == 127) row_start[n] = sc[127]; // total edge count
}

// ---------------- scan step 3: per-chunk exclusive scan + packed norms ----------------
__global__ __launch_bounds__(256) void scan_final_kernel(const int* __restrict__ deg, int n,
                                                         const int* __restrict__ partial,
                                                         int* __restrict__ row_start,
                                                         float2* __restrict__ norms) {
    __shared__ int sc[256];
    int b = blockIdx.x, t = threadIdx.x;
    int base = b * SCAN_CHUNK + t * 4;
    int v[4];
    int tsum = 0;
#pragma unroll
    for (int j = 0; j < 4; j++) {
        int idx = base + j;
        v[j] = (idx < n) ? deg[idx] : 0;
        tsum += v[j];
    }
    sc[t] = tsum;
    __syncthreads();
    for (int off = 1; off < 256; off <<= 1) {
        int val = sc[t];
        int add = (t >= off) ? sc[t - off] : 0;
        __syncthreads();
        sc[t] = val + add;
        __syncthreads();
    }
    int run = sc[t] - tsum + partial[b];
#pragma unroll
    for (int j = 0; j < 4; j++) {
        int idx = base + j;
        if (idx < n) {
            row_start[idx] = run;
            float d = (float)(v[j] > 0 ? v[j] : 1); // clip(deg, 1)
            norms[idx] = make_float2(rsqrtf(d), 1.0f / d);
            run += v[j];
        }
    }
}

// ---------------- edge scatter into CSR slots (atomic-free) ----------------
__global__ void scatter_edges_kernel(const int* __restrict__ src, const int* __restrict__ dst,
                                     const int* __restrict__ rank,
                                     const int* __restrict__ row_start,
                                     int E, int* __restrict__ srcs_sorted) {
    int i = blockIdx.x * blockDim.x + threadIdx.x;
    if (i < E) {
        srcs_sorted[row_start[dst[i]] + rank[i]] = src[i];
    }
}

// ---------------- convert W_mean|W_var into f16 Bt, wave-friendly layout ----------------
// Bt row ng = g*16 + i, g = w*4 + cg; cg 0/1 -> mean cols, cg 2/3 -> var cols
// actual col = w*32 + (cg&1)*16 + i;  Bt[ng][k] = W[k][col]
__global__ __launch_bounds__(256) void convert_B_kernel(const float* __restrict__ Wm,
                                                        const float* __restrict__ Wv,
                                                        f16* __restrict__ Bt) {
    int k = threadIdx.x;
    int ng = blockIdx.x;
    int g = ng >> 4, i = ng & 15;
    int w = g >> 2, cg = g & 3;
    int col = w * 32 + (cg & 1) * 16 + i;
    const float* srcW = (cg >= 2) ? Wv : Wm;
    Bt[ng * 256 + k] = (f16)srcW[k * 128 + col];
}

// ---------------- FUSED: edge count+rank (even blocks) | MFMA proj (odd blocks) ------
// Count path and proj path are data-independent (norms applied later in agg), so the
// memory-side atomic pass overlaps the BW-bound projection.
// proj: block = 4 waves. Wave w owns output cols [w*32, w*32+32) for mean & var.
// msg layout: node row = 256 f16 = interleaved (m_c, v_c) pairs, c in [0,128).
__global__ __launch_bounds__(256) void fused_count_proj_kernel(const int* __restrict__ dst,
                                                               int* __restrict__ deg,
                                                               int* __restrict__ rank,
                                                               const float* __restrict__ feat,
                                                               const f16* __restrict__ Bt,
                                                               f16* __restrict__ msg) {
    int b = blockIdx.x;
    if ((b & 1) == 0) {
        // ---- count + rank: 256 edges ----
        int i = (b >> 1) * 256 + threadIdx.x;   // E = E_BLOCKS*256 exact
        rank[i] = atomicAdd(&deg[dst[i]], 1);
        return;
    }
    // ---- projection tile ----
    int t = b >> 1;                              // 0 .. M_TILES-1
    int tid = threadIdx.x;
    int w = tid >> 6;
    int lane = tid & 63;
    int quad = lane >> 4;
    int l15 = lane & 15;

    // load B fragments: 4 col-groups x 8 k-frags (held in registers)
    half8 bfr[4][8];
#pragma unroll
    for (int cg = 0; cg < 4; cg++) {
        int g = w * 4 + cg;
        const f16* bp = Bt + (size_t)(g * 16 + l15) * 256 + quad * 8;
#pragma unroll
        for (int kf = 0; kf < 8; kf++) {
            bfr[cg][kf] = *(const half8*)(bp + kf * 32);
        }
    }

    int m0 = t * 16;
    half8 a[8];
    const float* ap = feat + (size_t)(m0 + l15) * 256 + quad * 8;
#pragma unroll
    for (int kf = 0; kf < 8; kf++) {
        floatx4 f0 = *(const floatx4*)(ap + kf * 32);
        floatx4 f1 = *(const floatx4*)(ap + kf * 32 + 4);
        half8 h;
        h[0] = (f16)f0.x; h[1] = (f16)f0.y; h[2] = (f16)f0.z; h[3] = (f16)f0.w;
        h[4] = (f16)f1.x; h[5] = (f16)f1.y; h[6] = (f16)f1.z; h[7] = (f16)f1.w;
        a[kf] = h;
    }

    floatx4 acc[4];
#pragma unroll
    for (int cg = 0; cg < 4; cg++) acc[cg] = (floatx4){0.f, 0.f, 0.f, 0.f};

#pragma unroll
    for (int cg = 0; cg < 4; cg++) {
#pragma unroll
        for (int kf = 0; kf < 8; kf++) {
            acc[cg] = __builtin_amdgcn_mfma_f32_16x16x32_f16(a[kf], bfr[cg][kf], acc[cg], 0, 0, 0);
        }
    }

    // epilogue: cg 0/1 = mean cols, cg 2/3 = var on same cols. NO norm here.
#pragma unroll
    for (int cg = 0; cg < 2; cg++) {
        int col = w * 32 + cg * 16 + l15;
#pragma unroll
        for (int r = 0; r < 4; r++) {
            int node = m0 + quad * 4 + r;
            float m = fmaxf(acc[cg][r], 0.f);
            float v = fmaxf(acc[cg + 2][r], 0.f);
            float att = __expf(-v); // GAMMA = 1
            half2v mv;
            mv[0] = (f16)(m * att);
            mv[1] = (f16)(v * att * att);
            *(half2v*)(msg + (size_t)node * 256 + 2 * col) = mv;
        }
    }
}

// ---------------- per-dst aggregation (wave per dst) + per-src & per-dst norms -------
// msg row: interleaved (m,v) pairs. lane l covers cols 2l, 2l+1 via one 8B load.
__global__ __launch_bounds__(256) void agg_kernel(const int* __restrict__ row_start,
                                                  const int* __restrict__ srcs,
                                                  const f16* __restrict__ msg,
                                                  const float2* __restrict__ norms,
                                                  float* __restrict__ out_mean,
                                                  float* __restrict__ out_var) {
    int d = blockIdx.x * 4 + (threadIdx.x >> 6);
    int lane = threadIdx.x & 63;
    int s0 = row_start[d];
    int s1 = row_start[d + 1];
    float am0 = 0.f, am1 = 0.f, av0 = 0.f, av1 = 0.f;
    int i = s0;
    for (; i + 3 < s1; i += 4) {
        int sa = srcs[i], sb = srcs[i + 1], sc = srcs[i + 2], sd = srcs[i + 3];
        float2 na = norms[sa], nb = norms[sb], nc = norms[sc], nd = norms[sd];
        half4 ha = *(const half4*)(msg + (size_t)sa * 256 + lane * 4);
        half4 hb = *(const half4*)(msg + (size_t)sb * 256 + lane * 4);
        half4 hc = *(const half4*)(msg + (size_t)sc * 256 + lane * 4);
        half4 hd = *(const half4*)(msg + (size_t)sd * 256 + lane * 4);
        am0 += (float)ha[0] * na.x + (float)hb[0] * nb.x + (float)hc[0] * nc.x + (float)hd[0] * nd.x;
        av0 += (float)ha[1] * na.y + (float)hb[1] * nb.y + (float)hc[1] * nc.y + (float)hd[1] * nd.y;
        am1 += (float)ha[2] * na.x + (float)hb[2] * nb.x + (float)hc[2] * nc.x + (float)hd[2] * nd.x;
        av1 += (float)ha[3] * na.y + (float)hb[3] * nb.y + (float)hc[3] * nc.y + (float)hd[3] * nd.y;
    }
    for (; i < s1; i++) {
        int sa = srcs[i];
        float2 na = norms[sa];
        half4 ha = *(const half4*)(msg + (size_t)sa * 256 + lane * 4);
        am0 += (float)ha[0] * na.x;
        av0 += (float)ha[1] * na.y;
        am1 += (float)ha[2] * na.x;
        av1 += (float)ha[3] * na.y;
    }
    float2 nd2 = norms[d];
    *(float2*)(out_mean + (size_t)d * 128 + lane * 2) = make_float2(am0 * nd2.x, am1 * nd2.x);
    *(float2*)(out_var + (size_t)d * 128 + lane * 2) = make_float2(av0 * nd2.y, av1 * nd2.y);
}

extern "C" void kernel_launch(void* const* d_in, const int* in_sizes, int n_in,
                              void* d_out, int out_size, void* d_ws, size_t ws_size,
                              hipStream_t stream) {
    const float* feat = (const float*)d_in[0];
    const float* Wm = (const float*)d_in[1];
    const float* Wv = (const float*)d_in[2];
    const int* src = (const int*)d_in[3];
    const int* dst = (const int*)d_in[4];
    float* out = (float*)d_out;

    const int N = N_NODES;
    const int E = N_EDGES;

    char* wsp = (char*)d_ws;
    auto carve = [&](size_t bytes) {
        char* p = wsp;
        wsp += (bytes + 255) & ~(size_t)255;
        return p;
    };
    f16* msg = (f16*)carve((size_t)N * 256 * sizeof(f16));   // interleaved (m,v), 51.2 MB
    f16* Bt = (f16*)carve((size_t)256 * 256 * sizeof(f16));  // 128 KB
    int* srcs_sorted = (int*)carve((size_t)E * 4);
    int* rank = (int*)carve((size_t)E * 4);
    int* deg = (int*)carve((size_t)N * 4);
    int* row_start = (int*)carve((size_t)(N + 1) * 4);
    float2* norms = (float2*)carve((size_t)N * sizeof(float2));
    int* partial = (int*)carve(128 * 4);

    hipMemsetAsync(deg, 0, (size_t)N * 4, stream);

    convert_B_kernel<<<256, 256, 0, stream>>>(Wm, Wv, Bt);
    fused_count_proj_kernel<<<E_BLOCKS + M_TILES, 256, 0, stream>>>(dst, deg, rank, feat, Bt, msg);
    scan_partial_kernel<<<SCAN_BLOCKS, 256, 0, stream>>>(deg, N, partial);
    scan_top_kernel<<<1, 128, 0, stream>>>(partial, SCAN_BLOCKS, row_start, N);
    scan_final_kernel<<<SCAN_BLOCKS, 256, 0, stream>>>(deg, N, partial, row_start, norms);
    scatter_edges_kernel<<<(E + 255) / 256, 256, 0, stream>>>(src, dst, rank, row_start, E,
                                                              srcs_sorted);
    agg_kernel<<<N / 4, 256, 0, stream>>>(row_start, srcs_sorted, msg, norms,
                                          out, out + (size_t)N * OUTF);
}